// Round 2
// baseline (8167.710 us; speedup 1.0000x reference)
//
#include <hip/hip_runtime.h>
#include <cstdint>
#include <cstddef>

#define T_STEPS 512
#define HID 40
#define GATES 120

// Fold MLP second linear into the next GRU's input weights:
// wih_eff[g][k] = sum_j wih[g][j] * w2[j][k];  bih_eff[g] = bih[g] + sum_j wih[g][j]*b2[j]
// (x_gru = w2^T-conv a + b2; sx = wih.x_gru + bih = wih_eff.a + bih_eff)
__global__ __launch_bounds__(64) void fold_w2(
    const float* __restrict__ g_wih,   // [4][120][40]
    const float* __restrict__ g_bih,   // [4][120]
    const float* __restrict__ mlp_w2,  // [3][40][40]
    const float* __restrict__ mlp_b2,  // [3][40]
    float* __restrict__ wih_eff,       // [3][120][40]
    float* __restrict__ bih_eff)       // [3][120]
{
    const int li = blockIdx.y;   // 0..2  (maps to g index li+1)
    const int g  = blockIdx.x;   // 0..119
    const int j  = threadIdx.x;  // 0..63
    const float* wrow = g_wih + ((size_t)(li + 1) * GATES + g) * HID;
    if (j < HID) {
        float acc = 0.f;
        #pragma unroll 8
        for (int k = 0; k < HID; ++k)
            acc += wrow[k] * mlp_w2[((size_t)li * HID + k) * HID + j];
        wih_eff[((size_t)li * GATES + g) * HID + j] = acc;
    }
    if (j == HID) {
        float acc = g_bih[(size_t)(li + 1) * GATES + g];
        #pragma unroll 8
        for (int k = 0; k < HID; ++k)
            acc += wrow[k] * mlp_b2[(size_t)li * HID + k];
        bih_eff[(size_t)li * GATES + g] = acc;
    }
}

// One wave (= one 64-thread block) per batch element, persistent over T steps.
// Lane l owns gate rows l and l+64. Gate weights live in VGPRs. All LDS
// traffic is intra-wave, so __syncthreads is wave-local (blockDim=64).
// Optional fused first-MLP-linear: a = leaky(w1.x + b1); gates dot over a
// with pre-folded wih_eff (w2 already absorbed).
template<int DIN, bool FUSE_MLP, bool WRITE_ALL>
__global__ __launch_bounds__(64, 2) void gru1w(
    const float* __restrict__ in,    // [CB, T, DIN]
    float* __restrict__ out,         // [CB, T, HID] or [CB, HID]
    const float* __restrict__ wih,   // [120, GDIM]  (effective if FUSE_MLP)
    const float* __restrict__ whh,   // [120, 40]
    const float* __restrict__ bih,   // [120]        (effective if FUSE_MLP)
    const float* __restrict__ bhh,   // [120]
    const float* __restrict__ mw1,   // [40,40] or null
    const float* __restrict__ mb1)   // [40] or null
{
    __shared__ float s_x[64];            // staged raw input x_t
    __shared__ float s_a[64];            // MLP activation (gate input if FUSE_MLP)
    __shared__ float s_h[HID];           // recurrent state
    __shared__ float s_sum[GATES];       // sx+sh per gate
    __shared__ float s_shn[HID];         // sh for n-gates
    __shared__ float s_w1[HID][44];      // stride 44 floats = 176B (16B aligned, conflict-free b128)

    const int lane = threadIdx.x;
    const int e    = blockIdx.x;

    if constexpr (FUSE_MLP) {
        for (int i = lane; i < HID * HID; i += 64)
            s_w1[i / HID][i % HID] = mw1[i];
    }
    float mb1r = 0.f;
    if (FUSE_MLP && lane < HID) mb1r = mb1[lane];

    // per-lane gate rows
    const int  g0   = lane;
    const bool has1 = lane < (GATES - 64);
    const int  g1   = has1 ? (64 + lane) : 0;

    float wi0[DIN], wi1[DIN], wh0[HID], wh1[HID];
    {
        const float4* wv = reinterpret_cast<const float4*>(wih);
        #pragma unroll
        for (int k = 0; k < DIN / 4; ++k) {
            reinterpret_cast<float4*>(wi0)[k] = wv[g0 * (DIN / 4) + k];
            reinterpret_cast<float4*>(wi1)[k] = wv[g1 * (DIN / 4) + k];
        }
        const float4* hv = reinterpret_cast<const float4*>(whh);
        #pragma unroll
        for (int k = 0; k < HID / 4; ++k) {
            reinterpret_cast<float4*>(wh0)[k] = hv[g0 * (HID / 4) + k];
            reinterpret_cast<float4*>(wh1)[k] = hv[g1 * (HID / 4) + k];
        }
    }
    const float bi0 = bih[g0], bh0 = bhh[g0];
    const float bi1 = has1 ? bih[g1] : 0.f;
    const float bh1 = has1 ? bhh[g1] : 0.f;

    if (lane < HID) s_h[lane] = 0.f;

    const float* inbase = in + (size_t)e * T_STEPS * DIN;
    float* outbase;
    if constexpr (WRITE_ALL) outbase = out + (size_t)e * T_STEPS * HID;
    else                     outbase = out + (size_t)e * HID;

    // prefetch x_0
    float xr = 0.f;
    if (lane < DIN) xr = inbase[lane];

    for (int t = 0; t < T_STEPS; ++t) {
        if (lane < DIN) s_x[lane] = xr;
        __syncthreads();   // wave-local: x_t staged, h_{t-1} visible

        // prefetch next step's input (overlaps all compute below)
        const int tn = (t + 1 < T_STEPS) ? t + 1 : t;
        if (lane < DIN) xr = inbase[(size_t)tn * DIN + lane];

        if constexpr (FUSE_MLP) {
            if (lane < HID) {
                float acc = mb1r;
                #pragma unroll
                for (int k = 0; k < HID / 4; ++k) {
                    const float4 xv = reinterpret_cast<const float4*>(s_x)[k];
                    const float4 wv = *reinterpret_cast<const float4*>(&s_w1[lane][4 * k]);
                    acc += wv.x * xv.x + wv.y * xv.y + wv.z * xv.z + wv.w * xv.w;
                }
                s_a[lane] = acc > 0.f ? acc : 0.01f * acc;
            }
            __syncthreads();
        }

        // ---- gate dot products: weights in VGPRs, operands broadcast from LDS ----
        const float* gv = FUSE_MLP ? s_a : s_x;
        float sx0 = bi0, sx1 = bi1, sh0 = bh0, sh1 = bh1;
        #pragma unroll
        for (int k = 0; k < DIN / 4; ++k) {
            const float4 v = reinterpret_cast<const float4*>(gv)[k];
            sx0 += wi0[4*k+0]*v.x + wi0[4*k+1]*v.y + wi0[4*k+2]*v.z + wi0[4*k+3]*v.w;
            sx1 += wi1[4*k+0]*v.x + wi1[4*k+1]*v.y + wi1[4*k+2]*v.z + wi1[4*k+3]*v.w;
        }
        #pragma unroll
        for (int k = 0; k < HID / 4; ++k) {
            const float4 v = reinterpret_cast<const float4*>(s_h)[k];
            sh0 += wh0[4*k+0]*v.x + wh0[4*k+1]*v.y + wh0[4*k+2]*v.z + wh0[4*k+3]*v.w;
            sh1 += wh1[4*k+0]*v.x + wh1[4*k+1]*v.y + wh1[4*k+2]*v.z + wh1[4*k+3]*v.w;
        }
        s_sum[g0] = sx0 + sh0;
        if (has1) {
            s_sum[g1] = sx1 + sh1;
            if (g1 >= 80) s_shn[g1 - 80] = sh1;
        }
        __syncthreads();   // gate sums ready

        if (lane < HID) {
            const float r   = 1.f / (1.f + __expf(-s_sum[lane]));
            const float z   = 1.f / (1.f + __expf(-s_sum[40 + lane]));
            const float pre = s_sum[80 + lane] + (r - 1.f) * s_shn[lane];
            const float ex  = __expf(-2.f * pre);
            const float n   = (1.f - ex) / (1.f + ex);
            const float hnew = (1.f - z) * n + z * s_h[lane];
            s_h[lane] = hnew;
            if constexpr (WRITE_ALL) outbase[(size_t)t * HID + lane] = hnew;
            else if (t == T_STEPS - 1) outbase[lane] = hnew;
        }
        // next iteration's first __syncthreads orders s_h update vs next reads
    }
}

// lay8: a = leaky(h @ w1^T + b1); t = a . w_last + b_last; out = sigmoid(t)
__global__ __launch_bounds__(256) void final_head(
    const float* __restrict__ hlast,  // [CB, 40]
    float* __restrict__ outp,         // [CB]
    const float* __restrict__ w1, const float* __restrict__ b1,
    const float* __restrict__ wl, const float* __restrict__ bl, int n)
{
    __shared__ float s_w1[HID][HID + 1];
    __shared__ float s_b1[HID];
    __shared__ float s_wl[HID];
    for (int i = threadIdx.x; i < HID * HID; i += 256) s_w1[i / HID][i % HID] = w1[i];
    if (threadIdx.x < HID) { s_b1[threadIdx.x] = b1[threadIdx.x]; s_wl[threadIdx.x] = wl[threadIdx.x]; }
    __syncthreads();
    const int e = blockIdx.x * 256 + threadIdx.x;
    if (e >= n) return;
    float h[HID];
    const float4* hv = reinterpret_cast<const float4*>(hlast + (size_t)e * HID);
    #pragma unroll
    for (int k = 0; k < HID / 4; ++k) reinterpret_cast<float4*>(h)[k] = hv[k];
    float acc = bl[0];
    #pragma unroll
    for (int u = 0; u < HID; ++u) {
        float a = s_b1[u];
        #pragma unroll
        for (int d = 0; d < HID; ++d) a += s_w1[u][d] * h[d];
        a = a > 0.f ? a : 0.01f * a;
        acc += a * s_wl[u];
    }
    outp[e] = 1.f / (1.f + __expf(-acc));
}

extern "C" void kernel_launch(void* const* d_in, const int* in_sizes, int n_in,
                              void* d_out, int out_size, void* d_ws, size_t ws_size,
                              hipStream_t stream)
{
    const float* x      = (const float*)d_in[0];
    const float* g0_wih = (const float*)d_in[1];
    const float* g0_whh = (const float*)d_in[2];
    const float* g0_bih = (const float*)d_in[3];
    const float* g0_bhh = (const float*)d_in[4];
    const float* g_wih  = (const float*)d_in[5];   // [4,120,40]
    const float* g_whh  = (const float*)d_in[6];   // [4,120,40]
    const float* g_bih  = (const float*)d_in[7];   // [4,120]
    const float* g_bhh  = (const float*)d_in[8];   // [4,120]
    const float* mlp_w1 = (const float*)d_in[9];   // [4,40,40]
    const float* mlp_b1 = (const float*)d_in[10];  // [4,40]
    const float* mlp_w2 = (const float*)d_in[11];  // [3,40,40]
    const float* mlp_b2 = (const float*)d_in[12];  // [3,40]
    const float* w_last = (const float*)d_in[13];  // [1,40]
    const float* b_last = (const float*)d_in[14];  // [1]

    const int B = in_sizes[0] / (T_STEPS * 20);
    float* out = (float*)d_out;

    // ws layout: [wih_eff 3*120*40][bih_eff 3*120][bufA][bufB]
    float* wih_eff = (float*)d_ws;
    float* bih_eff = wih_eff + 3 * GATES * HID;
    float* bufs    = bih_eff + 3 * GATES;
    size_t ws_rem  = ws_size - (size_t)(3 * GATES * HID + 3 * GATES) * sizeof(float);

    fold_w2<<<dim3(GATES, 3), 64, 0, stream>>>(g_wih, g_bih, mlp_w2, mlp_b2,
                                               wih_eff, bih_eff);

    int CB = B;
    while ((size_t)2 * CB * T_STEPS * HID * sizeof(float) > ws_rem && CB > 64) CB >>= 1;
    float* bufA = bufs;
    float* bufB = bufA + (size_t)CB * T_STEPS * HID;

    for (int c = 0; c < B; c += CB) {
        const float* xc = x + (size_t)c * T_STEPS * 20;
        const dim3 blk(64), grd(CB);

        // lay1: 2-layer GRU (no MLP)
        gru1w<20, false, true><<<grd, blk, 0, stream>>>(
            xc, bufA, g0_wih, g0_whh, g0_bih, g0_bhh, nullptr, nullptr);
        gru1w<40, false, true><<<grd, blk, 0, stream>>>(
            bufA, bufB, g_wih + 0 * 4800, g_whh + 0 * 4800, g_bih + 0 * 120, g_bhh + 0 * 120,
            nullptr, nullptr);
        // lay2+3: MLP0 (w2 folded) + GRU g[1]
        gru1w<40, true, true><<<grd, blk, 0, stream>>>(
            bufB, bufA, wih_eff + 0 * 4800, g_whh + 1 * 4800, bih_eff + 0 * 120, g_bhh + 1 * 120,
            mlp_w1 + 0 * 1600, mlp_b1 + 0 * 40);
        // lay4+5: MLP1 + GRU g[2]
        gru1w<40, true, true><<<grd, blk, 0, stream>>>(
            bufA, bufB, wih_eff + 1 * 4800, g_whh + 2 * 4800, bih_eff + 1 * 120, g_bhh + 2 * 120,
            mlp_w1 + 1 * 1600, mlp_b1 + 1 * 40);
        // lay6+7: MLP2 + GRU g[3]; only last h needed
        gru1w<40, true, false><<<grd, blk, 0, stream>>>(
            bufB, bufA, wih_eff + 2 * 4800, g_whh + 3 * 4800, bih_eff + 2 * 120, g_bhh + 3 * 120,
            mlp_w1 + 2 * 1600, mlp_b1 + 2 * 40);
        // lay8 head on h[:, -1]
        final_head<<<dim3((CB + 255) / 256), dim3(256), 0, stream>>>(
            bufA, out + c, mlp_w1 + 3 * 1600, mlp_b1 + 3 * 40, w_last, b_last, CB);
    }
}

// Round 3
// 2732.348 us; speedup vs baseline: 2.9893x; 2.9893x over previous
//
#include <hip/hip_runtime.h>
#include <cstdint>
#include <cstddef>

#define T_STEPS 512
#define HID 40
#define GATES 120

// Force a value to live in a VGPR (prevents rematerialization / re-loading weights).
__device__ __forceinline__ void pinf(float& x) { asm volatile("" : "+v"(x)); }
// Single-wave-block "barrier": lanes are lockstep, only LDS completion ordering needed.
__device__ __forceinline__ void wavesync() { asm volatile("s_waitcnt lgkmcnt(0)" ::: "memory"); }
__device__ __forceinline__ float bperm(int srclane, float v) {
    return __int_as_float(__builtin_amdgcn_ds_bpermute(srclane << 2, __float_as_int(v)));
}
__device__ __forceinline__ float sigm(float x) { return 1.f / (1.f + __expf(-x)); }

// Fold MLP second linear into the next GRU's input weights:
// wih_eff[g][j] = sum_k wih[g][k] * w2[k][j];  bih_eff[g] = bih[g] + sum_k wih[g][k]*b2[k]
__global__ __launch_bounds__(64) void fold_w2(
    const float* __restrict__ g_wih,   // [4][120][40]
    const float* __restrict__ g_bih,   // [4][120]
    const float* __restrict__ mlp_w2,  // [3][40][40]
    const float* __restrict__ mlp_b2,  // [3][40]
    float* __restrict__ wih_eff,       // [3][120][40]
    float* __restrict__ bih_eff)       // [3][120]
{
    const int li = blockIdx.y;   // 0..2  (maps to g index li+1)
    const int g  = blockIdx.x;   // 0..119
    const int j  = threadIdx.x;  // 0..63
    const float* wrow = g_wih + ((size_t)(li + 1) * GATES + g) * HID;
    if (j < HID) {
        float acc = 0.f;
        #pragma unroll 8
        for (int k = 0; k < HID; ++k)
            acc += wrow[k] * mlp_w2[((size_t)li * HID + k) * HID + j];
        wih_eff[((size_t)li * GATES + g) * HID + j] = acc;
    }
    if (j == HID) {
        float acc = g_bih[(size_t)(li + 1) * GATES + g];
        #pragma unroll 8
        for (int k = 0; k < HID; ++k)
            acc += wrow[k] * mlp_b2[(size_t)li * HID + k];
        bih_eff[(size_t)li * GATES + g] = acc;
    }
}

// One wave (= one 64-thread block) per batch element, persistent over T steps.
// Gate ownership: lane l<40: gA = r_l (gate l), gB = n_l (gate 80+l).
//                 lane 40..63: gA = z_{l-40} (gate l); lanes 40..55: gB = z_{l-16} (gate 24+l).
// r/n stay lane-local; z reaches its update lane via one ds_bpermute pair.
// NO barriers: single-wave lockstep + s_waitcnt lgkmcnt(0). Stores never drain.
// May run fully in-place (out == in): step t reads in[t] before writing out[t].
template<int DIN, bool FUSE_MLP, bool WRITE_ALL>
__global__ __launch_bounds__(64, 2) void gru1w(
    const float* __restrict__ in,    // [CB, T, DIN]
    float* __restrict__ out,         // [CB, T, HID] (may alias in)
    const float* __restrict__ wih,   // [120, DIN] (effective, w2-folded, if FUSE_MLP)
    const float* __restrict__ whh,   // [120, 40]
    const float* __restrict__ bih,   // [120]
    const float* __restrict__ bhh,   // [120]
    const float* __restrict__ mw1,   // [40,40] or null
    const float* __restrict__ mb1)   // [40] or null
{
    __shared__ float s_x[64];   // staged input x_t
    __shared__ float s_a[64];   // MLP activation (gate input if FUSE_MLP)
    __shared__ float s_h[64];   // recurrent state broadcast

    const int lane = threadIdx.x;
    const int e    = blockIdx.x;

    const int gA = lane;
    const int gB = (lane < 40) ? (80 + lane) : ((lane < 56) ? (24 + lane) : lane);

    float wiA[DIN], wiB[DIN], whA[HID], whB[HID], w1r[HID];
    {
        const float4* wv = reinterpret_cast<const float4*>(wih);
        #pragma unroll
        for (int k = 0; k < DIN / 4; ++k) {
            reinterpret_cast<float4*>(wiA)[k] = wv[gA * (DIN / 4) + k];
            reinterpret_cast<float4*>(wiB)[k] = wv[gB * (DIN / 4) + k];
        }
        const float4* hv = reinterpret_cast<const float4*>(whh);
        #pragma unroll
        for (int k = 0; k < HID / 4; ++k) {
            reinterpret_cast<float4*>(whA)[k] = hv[gA * (HID / 4) + k];
            reinterpret_cast<float4*>(whB)[k] = hv[gB * (HID / 4) + k];
        }
        if constexpr (FUSE_MLP) {
            const int r = (lane < HID) ? lane : 0;
            #pragma unroll
            for (int k = 0; k < HID / 4; ++k)
                reinterpret_cast<float4*>(w1r)[k] =
                    reinterpret_cast<const float4*>(mw1)[r * (HID / 4) + k];
        }
    }
    // Pin weights into VGPRs so the compiler cannot re-load them each step.
    #pragma unroll
    for (int k = 0; k < DIN; ++k) { pinf(wiA[k]); pinf(wiB[k]); }
    #pragma unroll
    for (int k = 0; k < HID; ++k) { pinf(whA[k]); pinf(whB[k]); }
    if constexpr (FUSE_MLP) {
        #pragma unroll
        for (int k = 0; k < HID; ++k) pinf(w1r[k]);
    }

    const float biA = bih[gA], bhA = bhh[gA];
    const float biB = bih[gB], bhB = bhh[gB];
    float mb1r = 0.f;
    if (FUSE_MLP && lane < HID) mb1r = mb1[lane];

    const float* inb  = in  + (size_t)e * T_STEPS * DIN;
    float*       outb = out + (size_t)e * T_STEPS * HID;

    float hreg = 0.f;
    s_h[lane] = 0.f;
    float xr = 0.f;
    if (lane < DIN) { s_x[lane] = inb[lane]; xr = inb[DIN + lane]; }
    wavesync();

    for (int t = 0; t < T_STEPS; ++t) {
        float sxA = biA, sxB = biB, shA = bhA, shB = bhB;

        if constexpr (FUSE_MLP) {
            // a = leaky(w1 . x + b1), w1 row in VGPRs, x broadcast from LDS
            float a = mb1r;
            #pragma unroll
            for (int k = 0; k < HID / 4; ++k) {
                const float4 xv = reinterpret_cast<float4*>(s_x)[k];
                a += w1r[4*k+0]*xv.x + w1r[4*k+1]*xv.y + w1r[4*k+2]*xv.z + w1r[4*k+3]*xv.w;
            }
            a = a > 0.f ? a : 0.01f * a;
            if (lane < HID) s_a[lane] = a;
            wavesync();
            #pragma unroll
            for (int k = 0; k < DIN / 4; ++k) {
                const float4 v = reinterpret_cast<float4*>(s_a)[k];
                sxA += wiA[4*k+0]*v.x + wiA[4*k+1]*v.y + wiA[4*k+2]*v.z + wiA[4*k+3]*v.w;
                sxB += wiB[4*k+0]*v.x + wiB[4*k+1]*v.y + wiB[4*k+2]*v.z + wiB[4*k+3]*v.w;
            }
        } else {
            #pragma unroll
            for (int k = 0; k < DIN / 4; ++k) {
                const float4 v = reinterpret_cast<float4*>(s_x)[k];
                sxA += wiA[4*k+0]*v.x + wiA[4*k+1]*v.y + wiA[4*k+2]*v.z + wiA[4*k+3]*v.w;
                sxB += wiB[4*k+0]*v.x + wiB[4*k+1]*v.y + wiB[4*k+2]*v.z + wiB[4*k+3]*v.w;
            }
        }
        #pragma unroll
        for (int k = 0; k < HID / 4; ++k) {
            const float4 v = reinterpret_cast<float4*>(s_h)[k];
            shA += whA[4*k+0]*v.x + whA[4*k+1]*v.y + whA[4*k+2]*v.z + whA[4*k+3]*v.w;
            shB += whB[4*k+0]*v.x + whB[4*k+1]*v.y + whB[4*k+2]*v.z + whB[4*k+3]*v.w;
        }
        const float sumA = sxA + shA;
        const float sumB = sxB + shB;
        // z_l lives in lane 40+l (sumA) for l<24, lane 16+l (sumB) for l>=24.
        // Execute bpermutes with ALL lanes active (inactive-source data is undefined).
        const float zA = bperm(40 + lane, sumA);
        const float zB = bperm(16 + lane, sumB);

        // stage next step's input + prefetch (after all s_x readers)
        if (t + 1 < T_STEPS) {
            if (lane < DIN) {
                s_x[lane] = xr;
                const int t2 = (t + 2 < T_STEPS) ? t + 2 : T_STEPS - 1;
                xr = inb[(size_t)t2 * DIN + lane];
            }
        }

        if (lane < HID) {
            const float r   = sigm(sumA);
            const float z   = sigm((lane < 24) ? zA : zB);
            const float pre = sxB + r * shB;          // x_n + r*(h_n) incl. biases
            const float ex  = __expf(-2.f * pre);
            const float n   = (1.f - ex) / (1.f + ex);
            hreg = (1.f - z) * n + z * hreg;
            s_h[lane] = hreg;
            if constexpr (WRITE_ALL) {
                outb[(size_t)t * HID + lane] = hreg;
            } else {
                if (t == T_STEPS - 1) outb[(size_t)t * HID + lane] = hreg;
            }
        }
        wavesync();   // h (and x) staged for next step
    }
}

// lay8: a = leaky(h @ w1^T + b1); t = a . w_last + b_last; out = sigmoid(t)
// Reads h_last strided out of the in-place activation buffer at [e][T-1][*].
__global__ __launch_bounds__(256) void final_head(
    const float* __restrict__ hbase,  // buf + (T-1)*HID
    float* __restrict__ outp,         // [CB]
    const float* __restrict__ w1, const float* __restrict__ b1,
    const float* __restrict__ wl, const float* __restrict__ bl, int n)
{
    __shared__ float s_w1[HID][HID + 1];
    __shared__ float s_b1[HID];
    __shared__ float s_wl[HID];
    for (int i = threadIdx.x; i < HID * HID; i += 256) s_w1[i / HID][i % HID] = w1[i];
    if (threadIdx.x < HID) { s_b1[threadIdx.x] = b1[threadIdx.x]; s_wl[threadIdx.x] = wl[threadIdx.x]; }
    __syncthreads();
    const int e = blockIdx.x * 256 + threadIdx.x;
    if (e >= n) return;
    float h[HID];
    const float4* hv = reinterpret_cast<const float4*>(hbase + (size_t)e * T_STEPS * HID);
    #pragma unroll
    for (int k = 0; k < HID / 4; ++k) reinterpret_cast<float4*>(h)[k] = hv[k];
    float acc = bl[0];
    #pragma unroll
    for (int u = 0; u < HID; ++u) {
        float a = s_b1[u];
        #pragma unroll
        for (int d = 0; d < HID; ++d) a += s_w1[u][d] * h[d];
        a = a > 0.f ? a : 0.01f * a;
        acc += a * s_wl[u];
    }
    outp[e] = 1.f / (1.f + __expf(-acc));
}

extern "C" void kernel_launch(void* const* d_in, const int* in_sizes, int n_in,
                              void* d_out, int out_size, void* d_ws, size_t ws_size,
                              hipStream_t stream)
{
    const float* x      = (const float*)d_in[0];
    const float* g0_wih = (const float*)d_in[1];
    const float* g0_whh = (const float*)d_in[2];
    const float* g0_bih = (const float*)d_in[3];
    const float* g0_bhh = (const float*)d_in[4];
    const float* g_wih  = (const float*)d_in[5];   // [4,120,40]
    const float* g_whh  = (const float*)d_in[6];   // [4,120,40]
    const float* g_bih  = (const float*)d_in[7];   // [4,120]
    const float* g_bhh  = (const float*)d_in[8];   // [4,120]
    const float* mlp_w1 = (const float*)d_in[9];   // [4,40,40]
    const float* mlp_b1 = (const float*)d_in[10];  // [4,40]
    const float* mlp_w2 = (const float*)d_in[11];  // [3,40,40]
    const float* mlp_b2 = (const float*)d_in[12];  // [3,40]
    const float* w_last = (const float*)d_in[13];  // [1,40]
    const float* b_last = (const float*)d_in[14];  // [1]

    const int B = in_sizes[0] / (T_STEPS * 20);
    float* out = (float*)d_out;

    // ws layout: [wih_eff 3*120*40][bih_eff 3*120][buf: CB*T*40] (single in-place buffer)
    float* wih_eff = (float*)d_ws;
    float* bih_eff = wih_eff + 3 * GATES * HID;
    float* buf     = bih_eff + 3 * GATES;
    const size_t ws_rem = ws_size - (size_t)(3 * GATES * HID + 3 * GATES) * sizeof(float);

    fold_w2<<<dim3(GATES, 3), 64, 0, stream>>>(g_wih, g_bih, mlp_w2, mlp_b2,
                                               wih_eff, bih_eff);

    int CB = B;
    while ((size_t)CB * T_STEPS * HID * sizeof(float) > ws_rem && CB > 64) CB >>= 1;

    for (int c = 0; c < B; c += CB) {
        const float* xc = x + (size_t)c * T_STEPS * 20;
        const dim3 blk(64), grd(CB);

        // lay1: 2-layer GRU; first into buf, second in-place
        gru1w<20, false, true><<<grd, blk, 0, stream>>>(
            xc, buf, g0_wih, g0_whh, g0_bih, g0_bhh, nullptr, nullptr);
        gru1w<40, false, true><<<grd, blk, 0, stream>>>(
            buf, buf, g_wih + 0 * 4800, g_whh + 0 * 4800, g_bih + 0 * 120, g_bhh + 0 * 120,
            nullptr, nullptr);
        // lay2+3: MLP0 (w2 folded) + GRU g[1], in-place
        gru1w<40, true, true><<<grd, blk, 0, stream>>>(
            buf, buf, wih_eff + 0 * 4800, g_whh + 1 * 4800, bih_eff + 0 * 120, g_bhh + 1 * 120,
            mlp_w1 + 0 * 1600, mlp_b1 + 0 * 40);
        // lay4+5: MLP1 + GRU g[2], in-place
        gru1w<40, true, true><<<grd, blk, 0, stream>>>(
            buf, buf, wih_eff + 1 * 4800, g_whh + 2 * 4800, bih_eff + 1 * 120, g_bhh + 2 * 120,
            mlp_w1 + 1 * 1600, mlp_b1 + 1 * 40);
        // lay6+7: MLP2 + GRU g[3], in-place; only t=T-1 stored (into [e][T-1][*])
        gru1w<40, true, false><<<grd, blk, 0, stream>>>(
            buf, buf, wih_eff + 2 * 4800, g_whh + 3 * 4800, bih_eff + 2 * 120, g_bhh + 3 * 120,
            mlp_w1 + 2 * 1600, mlp_b1 + 2 * 40);
        // lay8 head on h[:, -1] (strided read from the in-place buffer)
        final_head<<<dim3((CB + 255) / 256), dim3(256), 0, stream>>>(
            buf + (size_t)(T_STEPS - 1) * HID, out + c,
            mlp_w1 + 3 * 1600, mlp_b1 + 3 * 40, w_last, b_last, CB);
    }
}

// Round 4
// 2556.076 us; speedup vs baseline: 3.1954x; 1.0690x over previous
//
#include <hip/hip_runtime.h>
#include <cstdint>
#include <cstddef>

#define T_STEPS 512
#define HID 40
#define GATES 120

// Single-wave-block "barrier": lanes are lockstep, only LDS completion ordering needed.
// Never touches vmcnt, so global prefetch loads / output stores stay in flight.
__device__ __forceinline__ void wavesync() { asm volatile("s_waitcnt lgkmcnt(0)" ::: "memory"); }
__device__ __forceinline__ float bperm(int srclane, float v) {
    return __int_as_float(__builtin_amdgcn_ds_bpermute(srclane << 2, __float_as_int(v)));
}
__device__ __forceinline__ float sigm(float x) { return 1.f / (1.f + __expf(-x)); }

// Fold MLP second linear into the next GRU's input weights:
// wih_eff[g][j] = sum_k wih[g][k] * w2[k][j];  bih_eff[g] = bih[g] + sum_k wih[g][k]*b2[k]
__global__ __launch_bounds__(64) void fold_w2(
    const float* __restrict__ g_wih,   // [4][120][40]
    const float* __restrict__ g_bih,   // [4][120]
    const float* __restrict__ mlp_w2,  // [3][40][40]
    const float* __restrict__ mlp_b2,  // [3][40]
    float* __restrict__ wih_eff,       // [3][120][40]
    float* __restrict__ bih_eff)       // [3][120]
{
    const int li = blockIdx.y;   // 0..2  (maps to g index li+1)
    const int g  = blockIdx.x;   // 0..119
    const int j  = threadIdx.x;  // 0..63
    const float* wrow = g_wih + ((size_t)(li + 1) * GATES + g) * HID;
    if (j < HID) {
        float acc = 0.f;
        #pragma unroll 8
        for (int k = 0; k < HID; ++k)
            acc += wrow[k] * mlp_w2[((size_t)li * HID + k) * HID + j];
        wih_eff[((size_t)li * GATES + g) * HID + j] = acc;
    }
    if (j == HID) {
        float acc = g_bih[(size_t)(li + 1) * GATES + g];
        #pragma unroll 8
        for (int k = 0; k < HID; ++k)
            acc += wrow[k] * mlp_b2[(size_t)li * HID + k];
        bih_eff[(size_t)li * GATES + g] = acc;
    }
}

// One wave (= one 64-thread block) per batch element, persistent over T steps.
// Gate ownership: lane l<40: gA = r_l (gate l), gB = n_l (gate 80+l).
//                 lane 40..63: gA = z_{l-40}; lanes 40..55: gB = z_{l-16} (gate 24+l).
// r/n stay lane-local; z reaches its update lane via one ds_bpermute pair.
// Gate weights (wih,whh rows) live in VGPRs (~160 floats/lane); MLP w1 in LDS.
// amdgpu_waves_per_eu(2,2): exact occupancy 2 waves/SIMD -> 256-VGPR budget, so
// the backend keeps the loop-invariant weights resident instead of reloading.
template<int DIN, bool FUSE_MLP, bool WRITE_ALL>
__global__ __launch_bounds__(64)
__attribute__((amdgpu_waves_per_eu(2, 2)))
void gru1w(
    const float* __restrict__ in,    // [CB, T, DIN]
    float* __restrict__ out,         // [CB, T, HID] (may alias in)
    const float* __restrict__ wih,   // [120, DIN] (effective, w2-folded, if FUSE_MLP)
    const float* __restrict__ whh,   // [120, 40]
    const float* __restrict__ bih,   // [120]
    const float* __restrict__ bhh,   // [120]
    const float* __restrict__ mw1,   // [40,40] or null
    const float* __restrict__ mb1)   // [40] or null
{
    __shared__ float s_x[64];          // staged input x_t
    __shared__ float s_a[64];          // MLP activation (gate input if FUSE_MLP)
    __shared__ float s_h[64];          // recurrent state broadcast
    __shared__ float s_w1[HID][44];    // MLP w1, stride 44 (16B-aligned, 5-way max)

    const int lane = threadIdx.x;
    const int e    = blockIdx.x;

    const int gA = lane;
    const int gB = (lane < 40) ? (80 + lane) : ((lane < 56) ? (24 + lane) : lane);

    float wiA[DIN], wiB[DIN], whA[HID], whB[HID];
    {
        const float4* wv = reinterpret_cast<const float4*>(wih);
        #pragma unroll
        for (int k = 0; k < DIN / 4; ++k) {
            reinterpret_cast<float4*>(wiA)[k] = wv[gA * (DIN / 4) + k];
            reinterpret_cast<float4*>(wiB)[k] = wv[gB * (DIN / 4) + k];
        }
        const float4* hv = reinterpret_cast<const float4*>(whh);
        #pragma unroll
        for (int k = 0; k < HID / 4; ++k) {
            reinterpret_cast<float4*>(whA)[k] = hv[gA * (HID / 4) + k];
            reinterpret_cast<float4*>(whB)[k] = hv[gB * (HID / 4) + k];
        }
        if constexpr (FUSE_MLP) {
            for (int i = lane; i < HID * HID; i += 64)
                s_w1[i / HID][i % HID] = mw1[i];
        }
    }
    const float biA = bih[gA], bhA = bhh[gA];
    const float biB = bih[gB], bhB = bhh[gB];
    float mb1r = 0.f;
    if (FUSE_MLP && lane < HID) mb1r = mb1[lane];

    const float* inb  = in  + (size_t)e * T_STEPS * DIN;
    float*       outb = out + (size_t)e * T_STEPS * HID;

    float hreg = 0.f;
    s_h[lane] = 0.f;
    float xr = 0.f;
    if (lane < DIN) { s_x[lane] = inb[lane]; xr = inb[DIN + lane]; }
    wavesync();

    for (int t = 0; t < T_STEPS; ++t) {
        if constexpr (FUSE_MLP) {
            // a = leaky(w1 . x + b1); w1 row from LDS, x uniform-broadcast.
            // 4 independent accumulation chains.
            float a0 = 0.f, a1 = 0.f, a2 = 0.f, a3 = 0.f;
            const int r = (lane < HID) ? lane : 0;
            #pragma unroll
            for (int k = 0; k < HID / 4; ++k) {
                const float4 xv = reinterpret_cast<float4*>(s_x)[k];
                const float4 wv = *reinterpret_cast<const float4*>(&s_w1[r][4 * k]);
                a0 += wv.x * xv.x; a1 += wv.y * xv.y;
                a2 += wv.z * xv.z; a3 += wv.w * xv.w;
            }
            float a = mb1r + ((a0 + a2) + (a1 + a3));
            a = a > 0.f ? a : 0.01f * a;
            if (lane < HID) s_a[lane] = a;
            wavesync();
        }

        // ---- gate dots: weights in VGPRs, operands uniform-broadcast from LDS.
        // Component-wise float4 accumulators -> 16 independent FMA chains.
        const float* gv = FUSE_MLP ? s_a : s_x;
        float4 xA = {0,0,0,0}, xB = {0,0,0,0}, hA = {0,0,0,0}, hB = {0,0,0,0};
        #pragma unroll
        for (int k = 0; k < DIN / 4; ++k) {
            const float4 v = reinterpret_cast<const float4*>(gv)[k];
            xA.x += wiA[4*k+0]*v.x; xA.y += wiA[4*k+1]*v.y;
            xA.z += wiA[4*k+2]*v.z; xA.w += wiA[4*k+3]*v.w;
            xB.x += wiB[4*k+0]*v.x; xB.y += wiB[4*k+1]*v.y;
            xB.z += wiB[4*k+2]*v.z; xB.w += wiB[4*k+3]*v.w;
        }
        #pragma unroll
        for (int k = 0; k < HID / 4; ++k) {
            const float4 v = reinterpret_cast<const float4*>(s_h)[k];
            hA.x += whA[4*k+0]*v.x; hA.y += whA[4*k+1]*v.y;
            hA.z += whA[4*k+2]*v.z; hA.w += whA[4*k+3]*v.w;
            hB.x += whB[4*k+0]*v.x; hB.y += whB[4*k+1]*v.y;
            hB.z += whB[4*k+2]*v.z; hB.w += whB[4*k+3]*v.w;
        }
        const float sxB  = biB + ((xB.x + xB.z) + (xB.y + xB.w));
        const float shB  = bhB + ((hB.x + hB.z) + (hB.y + hB.w));
        const float sumA = (biA + bhA) + ((xA.x + xA.z) + (xA.y + xA.w))
                                       + ((hA.x + hA.z) + (hA.y + hA.w));
        const float sumB = sxB + shB;
        // z_l: lane 40+l (sumA) for l<24, lane 16+l (sumB) for l>=24. All lanes execute.
        const float zA = bperm(40 + lane, sumA);
        const float zB = bperm(16 + lane, sumB);

        // stage next step's input + prefetch t+2 (after all s_x readers)
        if (t + 1 < T_STEPS) {
            if (lane < DIN) {
                s_x[lane] = xr;
                const int t2 = (t + 2 < T_STEPS) ? t + 2 : T_STEPS - 1;
                xr = inb[(size_t)t2 * DIN + lane];
            }
        }

        if (lane < HID) {
            const float r   = sigm(sumA);
            const float z   = sigm((lane < 24) ? zA : zB);
            const float pre = sxB + r * shB;          // x_n + r*h_n incl. biases
            const float ex  = __expf(-2.f * pre);
            const float n   = (1.f - ex) / (1.f + ex);
            hreg = (1.f - z) * n + z * hreg;
            s_h[lane] = hreg;
            if constexpr (WRITE_ALL) {
                outb[(size_t)t * HID + lane] = hreg;
            } else {
                if (t == T_STEPS - 1) outb[(size_t)t * HID + lane] = hreg;
            }
        }
        wavesync();   // h (and x) staged for next step
    }
}

// lay8: a = leaky(h @ w1^T + b1); t = a . w_last + b_last; out = sigmoid(t)
// Reads h_last strided out of the in-place activation buffer at [e][T-1][*].
__global__ __launch_bounds__(256) void final_head(
    const float* __restrict__ hbase,  // buf + (T-1)*HID
    float* __restrict__ outp,         // [CB]
    const float* __restrict__ w1, const float* __restrict__ b1,
    const float* __restrict__ wl, const float* __restrict__ bl, int n)
{
    __shared__ float s_w1[HID][HID + 1];
    __shared__ float s_b1[HID];
    __shared__ float s_wl[HID];
    for (int i = threadIdx.x; i < HID * HID; i += 256) s_w1[i / HID][i % HID] = w1[i];
    if (threadIdx.x < HID) { s_b1[threadIdx.x] = b1[threadIdx.x]; s_wl[threadIdx.x] = wl[threadIdx.x]; }
    __syncthreads();
    const int e = blockIdx.x * 256 + threadIdx.x;
    if (e >= n) return;
    float h[HID];
    const float4* hv = reinterpret_cast<const float4*>(hbase + (size_t)e * T_STEPS * HID);
    #pragma unroll
    for (int k = 0; k < HID / 4; ++k) reinterpret_cast<float4*>(h)[k] = hv[k];
    float acc = bl[0];
    #pragma unroll
    for (int u = 0; u < HID; ++u) {
        float a = s_b1[u];
        #pragma unroll
        for (int d = 0; d < HID; ++d) a += s_w1[u][d] * h[d];
        a = a > 0.f ? a : 0.01f * a;
        acc += a * s_wl[u];
    }
    outp[e] = 1.f / (1.f + __expf(-acc));
}

extern "C" void kernel_launch(void* const* d_in, const int* in_sizes, int n_in,
                              void* d_out, int out_size, void* d_ws, size_t ws_size,
                              hipStream_t stream)
{
    const float* x      = (const float*)d_in[0];
    const float* g0_wih = (const float*)d_in[1];
    const float* g0_whh = (const float*)d_in[2];
    const float* g0_bih = (const float*)d_in[3];
    const float* g0_bhh = (const float*)d_in[4];
    const float* g_wih  = (const float*)d_in[5];   // [4,120,40]
    const float* g_whh  = (const float*)d_in[6];   // [4,120,40]
    const float* g_bih  = (const float*)d_in[7];   // [4,120]
    const float* g_bhh  = (const float*)d_in[8];   // [4,120]
    const float* mlp_w1 = (const float*)d_in[9];   // [4,40,40]
    const float* mlp_b1 = (const float*)d_in[10];  // [4,40]
    const float* mlp_w2 = (const float*)d_in[11];  // [3,40,40]
    const float* mlp_b2 = (const float*)d_in[12];  // [3,40]
    const float* w_last = (const float*)d_in[13];  // [1,40]
    const float* b_last = (const float*)d_in[14];  // [1]

    const int B = in_sizes[0] / (T_STEPS * 20);
    float* out = (float*)d_out;

    // ws layout: [wih_eff 3*120*40][bih_eff 3*120][buf: CB*T*40] (single in-place buffer)
    float* wih_eff = (float*)d_ws;
    float* bih_eff = wih_eff + 3 * GATES * HID;
    float* buf     = bih_eff + 3 * GATES;
    const size_t ws_rem = ws_size - (size_t)(3 * GATES * HID + 3 * GATES) * sizeof(float);

    fold_w2<<<dim3(GATES, 3), 64, 0, stream>>>(g_wih, g_bih, mlp_w2, mlp_b2,
                                               wih_eff, bih_eff);

    int CB = B;
    while ((size_t)CB * T_STEPS * HID * sizeof(float) > ws_rem && CB > 64) CB >>= 1;

    for (int c = 0; c < B; c += CB) {
        const float* xc = x + (size_t)c * T_STEPS * 20;
        const dim3 blk(64), grd(CB);

        // lay1: 2-layer GRU; first into buf, second in-place
        gru1w<20, false, true><<<grd, blk, 0, stream>>>(
            xc, buf, g0_wih, g0_whh, g0_bih, g0_bhh, nullptr, nullptr);
        gru1w<40, false, true><<<grd, blk, 0, stream>>>(
            buf, buf, g_wih + 0 * 4800, g_whh + 0 * 4800, g_bih + 0 * 120, g_bhh + 0 * 120,
            nullptr, nullptr);
        // lay2+3: MLP0 (w2 folded) + GRU g[1], in-place
        gru1w<40, true, true><<<grd, blk, 0, stream>>>(
            buf, buf, wih_eff + 0 * 4800, g_whh + 1 * 4800, bih_eff + 0 * 120, g_bhh + 1 * 120,
            mlp_w1 + 0 * 1600, mlp_b1 + 0 * 40);
        // lay4+5: MLP1 + GRU g[2], in-place
        gru1w<40, true, true><<<grd, blk, 0, stream>>>(
            buf, buf, wih_eff + 1 * 4800, g_whh + 2 * 4800, bih_eff + 1 * 120, g_bhh + 2 * 120,
            mlp_w1 + 1 * 1600, mlp_b1 + 1 * 40);
        // lay6+7: MLP2 + GRU g[3], in-place; only t=T-1 stored (into [e][T-1][*])
        gru1w<40, true, false><<<grd, blk, 0, stream>>>(
            buf, buf, wih_eff + 2 * 4800, g_whh + 3 * 4800, bih_eff + 2 * 120, g_bhh + 3 * 120,
            mlp_w1 + 2 * 1600, mlp_b1 + 2 * 40);
        // lay8 head on h[:, -1] (strided read from the in-place buffer)
        final_head<<<dim3((CB + 255) / 256), dim3(256), 0, stream>>>(
            buf + (size_t)(T_STEPS - 1) * HID, out + c,
            mlp_w1 + 3 * 1600, mlp_b1 + 3 * 40, w_last, b_last, CB);
    }
}